// Round 8
// baseline (1320.390 us; speedup 1.0000x reference)
//
#include <hip/hip_runtime.h>
#include <hip/hip_bf16.h>

typedef unsigned short u16;
typedef __bf16 bf16x8v __attribute__((ext_vector_type(8)));
typedef float f32x4v __attribute__((ext_vector_type(4)));
typedef float f32x4u __attribute__((ext_vector_type(4))) __attribute__((aligned(4)));

// ---------- bf16 helpers (RNE) ----------
__device__ __forceinline__ float bf2f(u16 u) {
    union { float f; unsigned int i; } c; c.i = ((unsigned int)u) << 16; return c.f;
}
__device__ __forceinline__ u16 f2bf(float f) {
    union { float f; unsigned int i; } c; c.f = f;
    unsigned int i = c.i;
    unsigned int lsb = (i >> 16) & 1u;
    i += 0x7fffu + lsb;
    return (u16)(i >> 16);
}
__device__ __forceinline__ float lo16(unsigned u) { return bf2f((u16)(u & 0xffff)); }
__device__ __forceinline__ float hi16(unsigned u) { return bf2f((u16)(u >> 16)); }
__device__ __forceinline__ unsigned pack2(float lo, float hi) {
    return (unsigned)f2bf(lo) | ((unsigned)f2bf(hi) << 16);
}

// load 8 fp32 from rowp[k..k+7] (guarded, zero-padded), convert to bf16x8 fragment
__device__ __forceinline__ bf16x8v load_cvt8(const float* __restrict__ rowp, int k, int kmax) {
    union { unsigned u[4]; bf16x8v v; } r;
#pragma unroll
    for (int g = 0; g < 2; ++g) {
        int kk = k + g * 4;
        float f0, f1, f2, f3;
        if (kk + 3 < kmax) {
            f32x4u q = *(const f32x4u*)(rowp + kk);
            f0 = q.x; f1 = q.y; f2 = q.z; f3 = q.w;
        } else {
            f0 = (kk + 0 < kmax) ? rowp[kk + 0] : 0.f;
            f1 = (kk + 1 < kmax) ? rowp[kk + 1] : 0.f;
            f2 = (kk + 2 < kmax) ? rowp[kk + 2] : 0.f;
            f3 = (kk + 3 < kmax) ? rowp[kk + 3] : 0.f;
        }
        r.u[g * 2]     = pack2(f0, f1);
        r.u[g * 2 + 1] = pack2(f2, f3);
    }
    return r.v;
}

// ---------- weight packing: Wt[n][k] = W[k][n], K padded with zeros ----------
__global__ void pack_w(const float* __restrict__ W, u16* __restrict__ Wt, int K, int Kpad) {
    int idx = blockIdx.x * 256 + threadIdx.x;
    if (idx >= 256 * Kpad) return;
    int n = idx / Kpad, k = idx % Kpad;
    float v = (k < K) ? W[k * 256 + n] : 0.f;
    Wt[idx] = f2bf(v);
}

// W_o packed for reordered concat: a_input = [a_message(256) | f_atoms(133) | pad(to 448)]
__global__ void pack_wo(const float* __restrict__ W_o, u16* __restrict__ Wt) {
    int idx = blockIdx.x * 256 + threadIdx.x;
    if (idx >= 256 * 448) return;
    int n = idx / 448, k = idx % 448;
    float v;
    if (k < 256)       v = W_o[(133 + k) * 256 + n];
    else if (k < 389)  v = W_o[(k - 256) * 256 + n];
    else               v = 0.f;
    Wt[idx] = f2bf(v);
}

// ---------- gather (16B/lane): amsg[a][h] = sum_j relu?(msg[a2b[a][j]][h]) * w_bonds[...] ----------
template <bool RELU>
__global__ __launch_bounds__(256)
void gather16(const u16* __restrict__ msg, const int* __restrict__ a2b,
              const float* __restrict__ w_bonds, u16* __restrict__ out, int nAtoms) {
    int t = threadIdx.x;
    int atom = blockIdx.x * 8 + (t >> 5);
    int co = (t & 31) * 8;
    if (atom >= nAtoms) return;
    float a[8] = {0.f, 0.f, 0.f, 0.f, 0.f, 0.f, 0.f, 0.f};
#pragma unroll
    for (int j = 0; j < 6; ++j) {
        int b = a2b[atom * 6 + j];
        float w = w_bonds[b];
        uint4 v = *(const uint4*)(msg + (size_t)b * 256 + co);
        unsigned p[4] = {v.x, v.y, v.z, v.w};
#pragma unroll
        for (int q = 0; q < 4; ++q) {
            float m0 = lo16(p[q]), m1 = hi16(p[q]);
            if (RELU) { m0 = fmaxf(m0, 0.f); m1 = fmaxf(m1, 0.f); }
            a[q * 2]     += w * m0;
            a[q * 2 + 1] += w * m1;
        }
    }
    uint4 o;
    o.x = pack2(a[0], a[1]); o.y = pack2(a[2], a[3]);
    o.z = pack2(a[4], a[5]); o.w = pack2(a[6], a[7]);
    *(uint4*)(out + (size_t)atom * 256 + co) = o;
}

// ---------- GEMM1: inp = f_bonds(fp32, stride 147) @ W_i^T, full-N, 1024 thr / 16 waves ----------
// Full 256-col weight in LDS (86 KB). Wave = 16 rows x 256 cols, acc 64 regs. A read once.
__global__ __launch_bounds__(1024, 4)
void gemm_in(const float* __restrict__ A, const u16* __restrict__ Bt, int M,
             u16* __restrict__ out0) {
    constexpr int KPAD = 160, KMAX = 147, ASTR = 147;
    constexpr int LSTR = KPAD + 8;
    __shared__ u16 Bs[256 * LSTR];
    const int tid = threadIdx.x;
    const int wave = tid >> 6;
    const int lane = tid & 63;
    const int mrow = lane & 15;
    const int quad = lane >> 4;

    constexpr int KC = KPAD / 8;
    for (int i = tid; i < 256 * KC; i += 1024) {
        int r = i / KC, kc = i % KC;
        *(uint4*)&Bs[r * LSTR + kc * 8] = *(const uint4*)&Bt[(size_t)r * KPAD + kc * 8];
    }
    __syncthreads();

    for (long chunk = blockIdx.x; chunk * 256 < (long)M; chunk += gridDim.x) {
        const long mbase = chunk * 256 + wave * 16;
        long r0 = mbase + mrow;
        if (r0 >= M) r0 = M - 1;
        const float* rowp = A + r0 * ASTR;

        f32x4v acc[16];
#pragma unroll
        for (int j = 0; j < 16; ++j) acc[j] = (f32x4v){0.f, 0.f, 0.f, 0.f};

#pragma unroll 2
        for (int k0 = 0; k0 < KPAD; k0 += 32) {
            bf16x8v a_frag = load_cvt8(rowp, k0 + quad * 8, KMAX);
#pragma unroll
            for (int jg = 0; jg < 4; ++jg) {
                bf16x8v b_frag[4];
#pragma unroll
                for (int j4 = 0; j4 < 4; ++j4)
                    b_frag[j4] = *(const bf16x8v*)&Bs[((jg * 4 + j4) * 16 + mrow) * LSTR + k0 + quad * 8];
#pragma unroll
                for (int j4 = 0; j4 < 4; ++j4)
                    acc[jg * 4 + j4] = __builtin_amdgcn_mfma_f32_16x16x32_bf16(
                        a_frag, b_frag[j4], acc[jg * 4 + j4], 0, 0, 0);
            }
        }

        // epilogue: C/D layout col=lane&15, row=quad*4+reg (16 rows per wave)
#pragma unroll
        for (int r = 0; r < 4; ++r) {
            long grow = mbase + quad * 4 + r;
            if (grow < M)
#pragma unroll
                for (int j = 0; j < 16; ++j)
                    out0[(size_t)grow * 256 + j * 16 + mrow] = f2bf(acc[j][r]);
        }
    }
}

// ---------- fused message-passing GEMM (full-N, 1024 thr / 16 waves, 4 waves/SIMD) ----------
// msg_new[b][:] = relu( inp[b] + (amsg[b2a[b]] - relu?(msgsrc[b2revb[b]])) @ Wh^T )
template <bool RELUV>
__global__ __launch_bounds__(1024, 4)
void gemm_mp(const u16* __restrict__ amsg, const u16* __restrict__ msgsrc,
             const int* __restrict__ b2a, const int* __restrict__ b2revb,
             const u16* __restrict__ Bt, int M,
             const u16* __restrict__ inp, u16* __restrict__ out0) {
    constexpr int KPAD = 256;
    constexpr int LSTR = KPAD + 8;
    __shared__ u16 Bs[256 * LSTR];            // 135 KB, 1 block/CU, 16 waves
    const int tid = threadIdx.x;
    const int wave = tid >> 6;
    const int lane = tid & 63;
    const int mrow = lane & 15;
    const int quad = lane >> 4;

    constexpr int KC = KPAD / 8;
    for (int i = tid; i < 256 * KC; i += 1024) {
        int r = i / KC, kc = i % KC;
        *(uint4*)&Bs[r * LSTR + kc * 8] = *(const uint4*)&Bt[(size_t)r * KPAD + kc * 8];
    }
    __syncthreads();

    for (long chunk = blockIdx.x; chunk * 256 < (long)M; chunk += gridDim.x) {
        const long mbase = chunk * 256 + wave * 16;
        long b = mbase + mrow;
        if (b >= M) b = M - 1;
        const size_t soff = (size_t)b2a[b] * 256 + quad * 8;
        const size_t roff = (size_t)b2revb[b] * 256 + quad * 8;

        f32x4v acc[16];
#pragma unroll
        for (int j = 0; j < 16; ++j) acc[j] = (f32x4v){0.f, 0.f, 0.f, 0.f};

#pragma unroll 2
        for (int k0 = 0; k0 < KPAD; k0 += 32) {
            uint4 va = *(const uint4*)&amsg[soff + k0];
            uint4 vr = *(const uint4*)&msgsrc[roff + k0];
            unsigned pa[4] = {va.x, va.y, va.z, va.w};
            unsigned pr[4] = {vr.x, vr.y, vr.z, vr.w};
            union { unsigned u[4]; bf16x8v v; } res;
#pragma unroll
            for (int p = 0; p < 4; ++p) {
                float rl = lo16(pr[p]), rh = hi16(pr[p]);
                if (RELUV) { rl = fmaxf(rl, 0.f); rh = fmaxf(rh, 0.f); }
                res.u[p] = pack2(lo16(pa[p]) - rl, hi16(pa[p]) - rh);
            }
            bf16x8v a_frag = res.v;
#pragma unroll
            for (int jg = 0; jg < 4; ++jg) {
                bf16x8v b_frag[4];
#pragma unroll
                for (int j4 = 0; j4 < 4; ++j4)
                    b_frag[j4] = *(const bf16x8v*)&Bs[((jg * 4 + j4) * 16 + mrow) * LSTR + k0 + quad * 8];
#pragma unroll
                for (int j4 = 0; j4 < 4; ++j4)
                    acc[jg * 4 + j4] = __builtin_amdgcn_mfma_f32_16x16x32_bf16(
                        a_frag, b_frag[j4], acc[jg * 4 + j4], 0, 0, 0);
            }
        }

        // epilogue: msg_new = relu(inp + acc)  (out0 may alias inp: own-idx read-then-write only)
#pragma unroll
        for (int r = 0; r < 4; ++r) {
            long grow = mbase + quad * 4 + r;
            if (grow < M)
#pragma unroll
                for (int j = 0; j < 16; ++j) {
                    size_t idx = (size_t)grow * 256 + j * 16 + mrow;
                    float s = bf2f(inp[idx]) + acc[j][r];
                    out0[idx] = f2bf(s > 0.f ? s : 0.f);
                }
        }
    }
}

// ---------- readout GEMM: hid = relu([amsg | f_atoms] @ Wo^T + b) ----------
// 128-col slices; SLICE IS blockIdx.x (fastest-varying) so both slices co-dispatch and share A.
__global__ __launch_bounds__(1024, 4)
void gemm_ro(const u16* __restrict__ A1, const float* __restrict__ A2,
             const u16* __restrict__ Bt, int M,
             const float* __restrict__ bias, float* __restrict__ outf) {
    constexpr int KPAD = 448, KSPLIT = 256, K2 = 192, KMAX2 = 133;
    constexpr int NROWS = 128;
    constexpr int LSTR = KPAD + 8;
    __shared__ u16 Bs[NROWS * LSTR];          // 116.7 KB
    const int tid = threadIdx.x;
    const int wave = tid >> 6;
    const int lane = tid & 63;
    const int mrow = lane & 15;
    const int quad = lane >> 4;
    const int nbase = blockIdx.x * NROWS;     // slice on x!

    constexpr int KC = KPAD / 8;
    for (int i = tid; i < NROWS * KC; i += 1024) {
        int r = i / KC, kc = i % KC;
        *(uint4*)&Bs[r * LSTR + kc * 8] =
            *(const uint4*)&Bt[(size_t)(nbase + r) * KPAD + kc * 8];
    }
    __syncthreads();

    for (long chunk = blockIdx.y; chunk * 256 < (long)M; chunk += gridDim.y) {
        const long mbase = chunk * 256 + wave * 16;
        long r0 = mbase + mrow;
        if (r0 >= M) r0 = M - 1;

        f32x4v acc[8];
#pragma unroll
        for (int j = 0; j < 8; ++j) acc[j] = (f32x4v){0.f, 0.f, 0.f, 0.f};

#pragma unroll 2
        for (int k0 = 0; k0 < KSPLIT; k0 += 32) {
            bf16x8v a_frag = *(const bf16x8v*)&A1[r0 * KSPLIT + k0 + quad * 8];
            bf16x8v b_frag[8];
#pragma unroll
            for (int j = 0; j < 8; ++j)
                b_frag[j] = *(const bf16x8v*)&Bs[(j * 16 + mrow) * LSTR + k0 + quad * 8];
#pragma unroll
            for (int j = 0; j < 8; ++j)
                acc[j] = __builtin_amdgcn_mfma_f32_16x16x32_bf16(
                    a_frag, b_frag[j], acc[j], 0, 0, 0);
        }
#pragma unroll 2
        for (int k0 = 0; k0 < K2; k0 += 32) {
            bf16x8v a_frag = load_cvt8(A2 + r0 * KMAX2, k0 + quad * 8, KMAX2);
            bf16x8v b_frag[8];
#pragma unroll
            for (int j = 0; j < 8; ++j)
                b_frag[j] = *(const bf16x8v*)&Bs[(j * 16 + mrow) * LSTR + KSPLIT + k0 + quad * 8];
#pragma unroll
            for (int j = 0; j < 8; ++j)
                acc[j] = __builtin_amdgcn_mfma_f32_16x16x32_bf16(
                    a_frag, b_frag[j], acc[j], 0, 0, 0);
        }

#pragma unroll
        for (int r = 0; r < 4; ++r) {
            long grow = mbase + quad * 4 + r;
            if (grow < M)
#pragma unroll
                for (int j = 0; j < 8; ++j) {
                    int gcol = nbase + j * 16 + mrow;
                    float s = acc[j][r] + bias[gcol];
                    outf[(size_t)grow * 256 + gcol] = s > 0.f ? s : 0.f;
                }
        }
    }
}

// ---------- per-molecule weighted mean (mol_ids sorted) ----------
__global__ __launch_bounds__(256)
void aggregate_kernel(const float* __restrict__ hid, const float* __restrict__ w_atoms,
                      const int* __restrict__ mol_ids, const float* __restrict__ deg,
                      float* __restrict__ out, int nAtoms) {
    int m = blockIdx.x;
    int t = threadIdx.x;
    int lo = 0, hi = nAtoms;
    while (lo < hi) { int mid = (lo + hi) >> 1; if (mol_ids[mid] < m) lo = mid + 1; else hi = mid; }
    int start = lo;
    lo = start; hi = nAtoms;
    while (lo < hi) { int mid = (lo + hi) >> 1; if (mol_ids[mid] < m + 1) lo = mid + 1; else hi = mid; }
    int end = lo;
    float acc = 0.f, wsum = 0.f;
    for (int a = start; a < end; ++a) {
        float w = w_atoms[a];
        wsum += w;
        acc += w * hid[(size_t)a * 256 + t];
    }
    float res = (wsum > 0.f) ? deg[m] * acc / wsum : 0.f;
    out[m * 256 + t] = res;
}

// ---------- launch ----------
extern "C" void kernel_launch(void* const* d_in, const int* in_sizes, int n_in,
                              void* d_out, int out_size, void* d_ws, size_t ws_size,
                              hipStream_t stream) {
    const float* f_atoms = (const float*)d_in[0];
    const float* f_bonds = (const float*)d_in[1];
    const float* w_atoms = (const float*)d_in[2];
    const float* w_bonds = (const float*)d_in[3];
    const float* W_i     = (const float*)d_in[4];
    const float* W_h     = (const float*)d_in[5];
    const float* W_o     = (const float*)d_in[6];
    const float* b_o     = (const float*)d_in[7];
    const float* deg     = (const float*)d_in[8];
    const int*   a2b     = (const int*)d_in[9];
    const int*   b2a     = (const int*)d_in[10];
    const int*   b2revb  = (const int*)d_in[11];
    const int*   mol_ids = (const int*)d_in[12];
    float* out = (float*)d_out;

    const int nB = 250000, nA = 100000, nM = 2000;

    // ws layout (bytes):
    //  P0 @ 0     : inp bf16 [250k][256] = 128 MB (becomes msgB in-place after iter-1 GEMM)
    //  P1 @ 128M  : msgA bf16 [250k][256] = 128 MB
    //  P2 @ 256M  : hid fp32 [100k][256] = 102.4 MB
    //  P3 @ 384M  : amsg bf16 [100k][256] = 51.2 MB
    //  P4 @ 435.2M: Wt_i (81,920) | Wt_h (131,072) | Wt_o (229,376)
    char* ws = (char*)d_ws;
    u16* inp    = (u16*)(ws);
    u16* msgA   = (u16*)(ws + 128000000L);
    float* hid  = (float*)(ws + 256000000L);
    u16* amsg   = (u16*)(ws + 384000000L);
    u16* wt_i   = (u16*)(ws + 435200000L);
    u16* wt_h   = (u16*)(ws + 435200000L + 81920L);
    u16* wt_o   = (u16*)(ws + 435200000L + 81920L + 131072L);

    if (ws_size < 435642368UL) return;

    dim3 b256(256), b1024(1024);
    pack_w<<<dim3((256 * 160 + 255) / 256), b256, 0, stream>>>(W_i, wt_i, 147, 160);
    pack_w<<<dim3((256 * 256 + 255) / 256), b256, 0, stream>>>(W_h, wt_h, 256, 256);
    pack_wo<<<dim3((256 * 448 + 255) / 256), b256, 0, stream>>>(W_o, wt_o);

    // GEMM1: inp = f_bonds @ W_i^T (fp32 A, conversion fused; full-N, A read once)
    gemm_in<<<dim3(977), b1024, 0, stream>>>(f_bonds, wt_i, nB, inp);

    // iteration 0 (msg == relu(inp) on the fly everywhere)
    gather16<true><<<dim3(nA / 8), b256, 0, stream>>>(inp, a2b, w_bonds, amsg, nA);
    gemm_mp<true><<<dim3(977), b1024, 0, stream>>>(
        amsg, inp, b2a, b2revb, wt_h, nB, inp, msgA);

    // iteration 1
    gather16<false><<<dim3(nA / 8), b256, 0, stream>>>(msgA, a2b, w_bonds, amsg, nA);
    gemm_mp<false><<<dim3(977), b1024, 0, stream>>>(
        amsg, msgA, b2a, b2revb, wt_h, nB, inp, inp);   // msgB in-place over inp

    // final readout (slice on grid.x so both slices co-dispatch)
    gather16<false><<<dim3(nA / 8), b256, 0, stream>>>(inp /*msgB*/, a2b, w_bonds, amsg, nA);
    gemm_ro<<<dim3(2, 391), b1024, 0, stream>>>(amsg, f_atoms, wt_o, nA, b_o, hid);

    aggregate_kernel<<<dim3(nM), b256, 0, stream>>>(hid, w_atoms, mol_ids, deg, out, nA);
}

// Round 9
// 855.919 us; speedup vs baseline: 1.5427x; 1.5427x over previous
//
#include <hip/hip_runtime.h>
#include <hip/hip_bf16.h>

typedef unsigned short u16;
typedef __bf16 bf16x8v __attribute__((ext_vector_type(8)));
typedef float f32x4v __attribute__((ext_vector_type(4)));
typedef float f32x4u __attribute__((ext_vector_type(4))) __attribute__((aligned(4)));

// ---------- bf16 helpers ----------
__device__ __forceinline__ float bf2f(u16 u) {
    union { float f; unsigned int i; } c; c.i = ((unsigned int)u) << 16; return c.f;
}
// exact RNE (used only in one-time weight packing)
__device__ __forceinline__ u16 f2bf(float f) {
    union { float f; unsigned int i; } c; c.f = f;
    unsigned int i = c.i;
    unsigned int lsb = (i >> 16) & 1u;
    i += 0x7fffu + lsb;
    return (u16)(i >> 16);
}
__device__ __forceinline__ float lo16(unsigned u) { return bf2f((u16)(u & 0xffff)); }
__device__ __forceinline__ float hi16(unsigned u) { return bf2f((u16)(u >> 16)); }
// fast packed round-half-up bf16x2: bits+0x8000 then byte-perm (v_perm_b32), 3 insts/pair
__device__ __forceinline__ unsigned pack2(float lo, float hi) {
    union { float f; unsigned int i; } a, b; a.f = lo; b.f = hi;
    return __builtin_amdgcn_perm(b.i + 0x8000u, a.i + 0x8000u, 0x07060302u);
}

// load 8 fp32 from rowp[k..k+7] (guarded, zero-padded), convert to bf16x8 fragment
__device__ __forceinline__ bf16x8v load_cvt8(const float* __restrict__ rowp, int k, int kmax) {
    union { unsigned u[4]; bf16x8v v; } r;
#pragma unroll
    for (int g = 0; g < 2; ++g) {
        int kk = k + g * 4;
        float f0, f1, f2, f3;
        if (kk + 3 < kmax) {
            f32x4u q = *(const f32x4u*)(rowp + kk);
            f0 = q.x; f1 = q.y; f2 = q.z; f3 = q.w;
        } else {
            f0 = (kk + 0 < kmax) ? rowp[kk + 0] : 0.f;
            f1 = (kk + 1 < kmax) ? rowp[kk + 1] : 0.f;
            f2 = (kk + 2 < kmax) ? rowp[kk + 2] : 0.f;
            f3 = (kk + 3 < kmax) ? rowp[kk + 3] : 0.f;
        }
        r.u[g * 2]     = pack2(f0, f1);
        r.u[g * 2 + 1] = pack2(f2, f3);
    }
    return r.v;
}

// ---------- weight packing: Wt[n][k] = W[k][n], K padded with zeros ----------
__global__ void pack_w(const float* __restrict__ W, u16* __restrict__ Wt, int K, int Kpad) {
    int idx = blockIdx.x * 256 + threadIdx.x;
    if (idx >= 256 * Kpad) return;
    int n = idx / Kpad, k = idx % Kpad;
    float v = (k < K) ? W[k * 256 + n] : 0.f;
    Wt[idx] = f2bf(v);
}

// W_o packed for reordered concat: a_input = [a_message(256) | f_atoms(133) | pad(to 448)]
__global__ void pack_wo(const float* __restrict__ W_o, u16* __restrict__ Wt) {
    int idx = blockIdx.x * 256 + threadIdx.x;
    if (idx >= 256 * 448) return;
    int n = idx / 448, k = idx % 448;
    float v;
    if (k < 256)       v = W_o[(133 + k) * 256 + n];
    else if (k < 389)  v = W_o[(k - 256) * 256 + n];
    else               v = 0.f;
    Wt[idx] = f2bf(v);
}

// ---------- gather (16B/lane): amsg[a][h] = sum_j relu?(msg[a2b[a][j]][h]) * w_bonds[...] ----------
template <bool RELU>
__global__ __launch_bounds__(256)
void gather16(const u16* __restrict__ msg, const int* __restrict__ a2b,
              const float* __restrict__ w_bonds, u16* __restrict__ out, int nAtoms) {
    int t = threadIdx.x;
    int atom = blockIdx.x * 8 + (t >> 5);
    int co = (t & 31) * 8;
    if (atom >= nAtoms) return;
    float a[8] = {0.f, 0.f, 0.f, 0.f, 0.f, 0.f, 0.f, 0.f};
#pragma unroll
    for (int j = 0; j < 6; ++j) {
        int b = a2b[atom * 6 + j];
        float w = w_bonds[b];
        uint4 v = *(const uint4*)(msg + (size_t)b * 256 + co);
        unsigned p[4] = {v.x, v.y, v.z, v.w};
#pragma unroll
        for (int q = 0; q < 4; ++q) {
            float m0 = lo16(p[q]), m1 = hi16(p[q]);
            if (RELU) { m0 = fmaxf(m0, 0.f); m1 = fmaxf(m1, 0.f); }
            a[q * 2]     += w * m0;
            a[q * 2 + 1] += w * m1;
        }
    }
    uint4 o;
    o.x = pack2(a[0], a[1]); o.y = pack2(a[2], a[3]);
    o.z = pack2(a[4], a[5]); o.w = pack2(a[6], a[7]);
    *(uint4*)(out + (size_t)atom * 256 + co) = o;
}

// ---------- GEMM1: inp = f_bonds(fp32, stride 147) @ W_i^T ----------
// Full-N weight in LDS (86 KB). 768 thr / 12 waves (3 waves/SIMD, reg cap 170 -> no spill).
// Wave = 16 rows x 256 cols, acc 64 AGPR. A read exactly once.
__global__ __launch_bounds__(768, 3)
void gemm_in(const float* __restrict__ A, const u16* __restrict__ Bt, int M,
             u16* __restrict__ out0) {
    constexpr int KPAD = 160, KMAX = 147, ASTR = 147;
    constexpr int LSTR = KPAD + 8;
    __shared__ u16 Bs[256 * LSTR];
    const int tid = threadIdx.x;
    const int wave = tid >> 6;
    const int lane = tid & 63;
    const int mrow = lane & 15;
    const int quad = lane >> 4;

    constexpr int KC = KPAD / 8;
    for (int i = tid; i < 256 * KC; i += 768) {
        int r = i / KC, kc = i % KC;
        *(uint4*)&Bs[r * LSTR + kc * 8] = *(const uint4*)&Bt[(size_t)r * KPAD + kc * 8];
    }
    __syncthreads();

    for (long chunk = blockIdx.x; chunk * 192 < (long)M; chunk += gridDim.x) {
        const long mbase = chunk * 192 + wave * 16;
        long r0 = mbase + mrow;
        if (r0 >= M) r0 = M - 1;
        const float* rowp = A + r0 * ASTR;

        f32x4v acc[16];
#pragma unroll
        for (int j = 0; j < 16; ++j) acc[j] = (f32x4v){0.f, 0.f, 0.f, 0.f};

#pragma unroll 2
        for (int k0 = 0; k0 < KPAD; k0 += 32) {
            bf16x8v a_frag = load_cvt8(rowp, k0 + quad * 8, KMAX);
#pragma unroll
            for (int jg = 0; jg < 4; ++jg) {
                bf16x8v b_frag[4];
#pragma unroll
                for (int j4 = 0; j4 < 4; ++j4)
                    b_frag[j4] = *(const bf16x8v*)&Bs[((jg * 4 + j4) * 16 + mrow) * LSTR + k0 + quad * 8];
#pragma unroll
                for (int j4 = 0; j4 < 4; ++j4)
                    acc[jg * 4 + j4] = __builtin_amdgcn_mfma_f32_16x16x32_bf16(
                        a_frag, b_frag[j4], acc[jg * 4 + j4], 0, 0, 0);
            }
        }

        // epilogue: C/D layout col=lane&15, row=quad*4+reg
#pragma unroll
        for (int r = 0; r < 4; ++r) {
            long grow = mbase + quad * 4 + r;
            if (grow < M)
#pragma unroll
                for (int j = 0; j < 16; ++j)
                    out0[(size_t)grow * 256 + j * 16 + mrow] = (u16)(pack2(acc[j][r], 0.f) & 0xffff);
        }
    }
}

// ---------- fused message-passing GEMM (full-N, 768 thr / 12 waves, 3 waves/SIMD) ----------
// msg_new[b][:] = relu( inp[b] + (amsg[b2a[b]] - relu?(msgsrc[b2revb[b]])) @ Wh^T )
template <bool RELUV>
__global__ __launch_bounds__(768, 3)
void gemm_mp(const u16* __restrict__ amsg, const u16* __restrict__ msgsrc,
             const int* __restrict__ b2a, const int* __restrict__ b2revb,
             const u16* __restrict__ Bt, int M,
             const u16* __restrict__ inp, u16* __restrict__ out0) {
    constexpr int KPAD = 256;
    constexpr int LSTR = KPAD + 8;
    __shared__ u16 Bs[256 * LSTR];            // 135 KB, 1 block/CU, 12 waves
    const int tid = threadIdx.x;
    const int wave = tid >> 6;
    const int lane = tid & 63;
    const int mrow = lane & 15;
    const int quad = lane >> 4;

    constexpr int KC = KPAD / 8;
    for (int i = tid; i < 256 * KC; i += 768) {
        int r = i / KC, kc = i % KC;
        *(uint4*)&Bs[r * LSTR + kc * 8] = *(const uint4*)&Bt[(size_t)r * KPAD + kc * 8];
    }
    __syncthreads();

    for (long chunk = blockIdx.x; chunk * 192 < (long)M; chunk += gridDim.x) {
        const long mbase = chunk * 192 + wave * 16;
        long b = mbase + mrow;
        if (b >= M) b = M - 1;
        const size_t soff = (size_t)b2a[b] * 256 + quad * 8;
        const size_t roff = (size_t)b2revb[b] * 256 + quad * 8;

        f32x4v acc[16];
#pragma unroll
        for (int j = 0; j < 16; ++j) acc[j] = (f32x4v){0.f, 0.f, 0.f, 0.f};

#pragma unroll 2
        for (int k0 = 0; k0 < KPAD; k0 += 32) {
            uint4 va = *(const uint4*)&amsg[soff + k0];
            uint4 vr = *(const uint4*)&msgsrc[roff + k0];
            unsigned pa[4] = {va.x, va.y, va.z, va.w};
            unsigned pr[4] = {vr.x, vr.y, vr.z, vr.w};
            union { unsigned u[4]; bf16x8v v; } res;
#pragma unroll
            for (int p = 0; p < 4; ++p) {
                float rl = lo16(pr[p]), rh = hi16(pr[p]);
                if (RELUV) { rl = fmaxf(rl, 0.f); rh = fmaxf(rh, 0.f); }
                res.u[p] = pack2(lo16(pa[p]) - rl, hi16(pa[p]) - rh);
            }
            bf16x8v a_frag = res.v;
#pragma unroll
            for (int jg = 0; jg < 4; ++jg) {
                bf16x8v b_frag[4];
#pragma unroll
                for (int j4 = 0; j4 < 4; ++j4)
                    b_frag[j4] = *(const bf16x8v*)&Bs[((jg * 4 + j4) * 16 + mrow) * LSTR + k0 + quad * 8];
#pragma unroll
                for (int j4 = 0; j4 < 4; ++j4)
                    acc[jg * 4 + j4] = __builtin_amdgcn_mfma_f32_16x16x32_bf16(
                        a_frag, b_frag[j4], acc[jg * 4 + j4], 0, 0, 0);
            }
        }

        // epilogue: msg_new = relu(inp + acc)  (out0 may alias inp: own-idx read-then-write only)
#pragma unroll
        for (int r = 0; r < 4; ++r) {
            long grow = mbase + quad * 4 + r;
            if (grow < M)
#pragma unroll
                for (int j = 0; j < 16; ++j) {
                    size_t idx = (size_t)grow * 256 + j * 16 + mrow;
                    float s = bf2f(inp[idx]) + acc[j][r];
                    s = s > 0.f ? s : 0.f;
                    out0[idx] = (u16)(pack2(s, 0.f) & 0xffff);
                }
        }
    }
}

// ---------- readout GEMM: hid = relu([amsg | f_atoms] @ Wo^T + b), 128-col slices ----------
// (A operands total ~104 MB -> L3-resident across slices; 512 thr, wave 32 rows x 128 cols)
__global__ __launch_bounds__(512, 2)
void gemm_ro(const u16* __restrict__ A1, const float* __restrict__ A2,
             const u16* __restrict__ Bt, int M,
             const float* __restrict__ bias, float* __restrict__ outf) {
    constexpr int KPAD = 448, KSPLIT = 256, K2 = 192, KMAX2 = 133;
    constexpr int NROWS = 128;
    constexpr int LSTR = KPAD + 8;
    __shared__ u16 Bs[NROWS * LSTR];
    const int tid = threadIdx.x;
    const int wave = tid >> 6;
    const int lane = tid & 63;
    const int mrow = lane & 15;
    const int quad = lane >> 4;
    const int nbase = blockIdx.x * NROWS;     // slice on fastest-varying dim

    constexpr int KC = KPAD / 8;
    for (int i = tid; i < NROWS * KC; i += 512) {
        int r = i / KC, kc = i % KC;
        *(uint4*)&Bs[r * LSTR + kc * 8] =
            *(const uint4*)&Bt[(size_t)(nbase + r) * KPAD + kc * 8];
    }
    __syncthreads();

    for (long chunk = blockIdx.y; chunk * 256 < (long)M; chunk += gridDim.y) {
        const long mbase = chunk * 256 + wave * 32;
        long row[2];
#pragma unroll
        for (int t = 0; t < 2; ++t) {
            long r = mbase + t * 16 + mrow;
            if (r >= M) r = M - 1;
            row[t] = r;
        }

        f32x4v acc[2][8];
#pragma unroll
        for (int t = 0; t < 2; ++t)
#pragma unroll
            for (int j = 0; j < 8; ++j) acc[t][j] = (f32x4v){0.f, 0.f, 0.f, 0.f};

#pragma unroll 2
        for (int k0 = 0; k0 < KSPLIT; k0 += 32) {
            bf16x8v a_frag[2], b_frag[8];
#pragma unroll
            for (int t = 0; t < 2; ++t)
                a_frag[t] = *(const bf16x8v*)&A1[row[t] * KSPLIT + k0 + quad * 8];
#pragma unroll
            for (int j = 0; j < 8; ++j)
                b_frag[j] = *(const bf16x8v*)&Bs[(j * 16 + mrow) * LSTR + k0 + quad * 8];
#pragma unroll
            for (int t = 0; t < 2; ++t)
#pragma unroll
                for (int j = 0; j < 8; ++j)
                    acc[t][j] = __builtin_amdgcn_mfma_f32_16x16x32_bf16(
                        a_frag[t], b_frag[j], acc[t][j], 0, 0, 0);
        }
#pragma unroll 2
        for (int k0 = 0; k0 < K2; k0 += 32) {
            bf16x8v a_frag[2], b_frag[8];
#pragma unroll
            for (int t = 0; t < 2; ++t)
                a_frag[t] = load_cvt8(A2 + row[t] * KMAX2, k0 + quad * 8, KMAX2);
#pragma unroll
            for (int j = 0; j < 8; ++j)
                b_frag[j] = *(const bf16x8v*)&Bs[(j * 16 + mrow) * LSTR + KSPLIT + k0 + quad * 8];
#pragma unroll
            for (int t = 0; t < 2; ++t)
#pragma unroll
                for (int j = 0; j < 8; ++j)
                    acc[t][j] = __builtin_amdgcn_mfma_f32_16x16x32_bf16(
                        a_frag[t], b_frag[j], acc[t][j], 0, 0, 0);
        }

#pragma unroll
        for (int t = 0; t < 2; ++t)
#pragma unroll
            for (int r = 0; r < 4; ++r) {
                long grow = mbase + t * 16 + quad * 4 + r;
                if (grow < M)
#pragma unroll
                    for (int j = 0; j < 8; ++j) {
                        int gcol = nbase + j * 16 + mrow;
                        float s = acc[t][j][r] + bias[gcol];
                        outf[(size_t)grow * 256 + gcol] = s > 0.f ? s : 0.f;
                    }
            }
    }
}

// ---------- per-molecule weighted mean (mol_ids sorted) ----------
__global__ __launch_bounds__(256)
void aggregate_kernel(const float* __restrict__ hid, const float* __restrict__ w_atoms,
                      const int* __restrict__ mol_ids, const float* __restrict__ deg,
                      float* __restrict__ out, int nAtoms) {
    int m = blockIdx.x;
    int t = threadIdx.x;
    int lo = 0, hi = nAtoms;
    while (lo < hi) { int mid = (lo + hi) >> 1; if (mol_ids[mid] < m) lo = mid + 1; else hi = mid; }
    int start = lo;
    lo = start; hi = nAtoms;
    while (lo < hi) { int mid = (lo + hi) >> 1; if (mol_ids[mid] < m + 1) lo = mid + 1; else hi = mid; }
    int end = lo;
    float acc = 0.f, wsum = 0.f;
    for (int a = start; a < end; ++a) {
        float w = w_atoms[a];
        wsum += w;
        acc += w * hid[(size_t)a * 256 + t];
    }
    float res = (wsum > 0.f) ? deg[m] * acc / wsum : 0.f;
    out[m * 256 + t] = res;
}

// ---------- launch ----------
extern "C" void kernel_launch(void* const* d_in, const int* in_sizes, int n_in,
                              void* d_out, int out_size, void* d_ws, size_t ws_size,
                              hipStream_t stream) {
    const float* f_atoms = (const float*)d_in[0];
    const float* f_bonds = (const float*)d_in[1];
    const float* w_atoms = (const float*)d_in[2];
    const float* w_bonds = (const float*)d_in[3];
    const float* W_i     = (const float*)d_in[4];
    const float* W_h     = (const float*)d_in[5];
    const float* W_o     = (const float*)d_in[6];
    const float* b_o     = (const float*)d_in[7];
    const float* deg     = (const float*)d_in[8];
    const int*   a2b     = (const int*)d_in[9];
    const int*   b2a     = (const int*)d_in[10];
    const int*   b2revb  = (const int*)d_in[11];
    const int*   mol_ids = (const int*)d_in[12];
    float* out = (float*)d_out;

    const int nB = 250000, nA = 100000, nM = 2000;

    // ws layout (bytes):
    //  P0 @ 0     : inp bf16 [250k][256] = 128 MB (becomes msgB in-place after iter-1 GEMM)
    //  P1 @ 128M  : msgA bf16 [250k][256] = 128 MB
    //  P2 @ 256M  : hid fp32 [100k][256] = 102.4 MB
    //  P3 @ 384M  : amsg bf16 [100k][256] = 51.2 MB
    //  P4 @ 435.2M: Wt_i (81,920) | Wt_h (131,072) | Wt_o (229,376)
    char* ws = (char*)d_ws;
    u16* inp    = (u16*)(ws);
    u16* msgA   = (u16*)(ws + 128000000L);
    float* hid  = (float*)(ws + 256000000L);
    u16* amsg   = (u16*)(ws + 384000000L);
    u16* wt_i   = (u16*)(ws + 435200000L);
    u16* wt_h   = (u16*)(ws + 435200000L + 81920L);
    u16* wt_o   = (u16*)(ws + 435200000L + 81920L + 131072L);

    if (ws_size < 435642368UL) return;

    dim3 b256(256), b768(768), b512(512);
    pack_w<<<dim3((256 * 160 + 255) / 256), b256, 0, stream>>>(W_i, wt_i, 147, 160);
    pack_w<<<dim3((256 * 256 + 255) / 256), b256, 0, stream>>>(W_h, wt_h, 256, 256);
    pack_wo<<<dim3((256 * 448 + 255) / 256), b256, 0, stream>>>(W_o, wt_o);

    const int gMP = (nB + 191) / 192;   // 1303 chunks of 192 rows

    // GEMM1: inp = f_bonds @ W_i^T (fp32 A, conversion fused; full-N, A read once)
    gemm_in<<<dim3(gMP), b768, 0, stream>>>(f_bonds, wt_i, nB, inp);

    // iteration 0 (msg == relu(inp) on the fly everywhere)
    gather16<true><<<dim3(nA / 8), b256, 0, stream>>>(inp, a2b, w_bonds, amsg, nA);
    gemm_mp<true><<<dim3(gMP), b768, 0, stream>>>(
        amsg, inp, b2a, b2revb, wt_h, nB, inp, msgA);

    // iteration 1
    gather16<false><<<dim3(nA / 8), b256, 0, stream>>>(msgA, a2b, w_bonds, amsg, nA);
    gemm_mp<false><<<dim3(gMP), b768, 0, stream>>>(
        amsg, msgA, b2a, b2revb, wt_h, nB, inp, inp);   // msgB in-place over inp

    // final readout
    gather16<false><<<dim3(nA / 8), b256, 0, stream>>>(inp /*msgB*/, a2b, w_bonds, amsg, nA);
    gemm_ro<<<dim3(2, 391), b512, 0, stream>>>(amsg, f_atoms, wt_o, nA, b_o, hid);

    aggregate_kernel<<<dim3(nM), b256, 0, stream>>>(hid, w_atoms, mol_ids, deg, out, nA);
}